// Round 13
// baseline (110.279 us; speedup 1.0000x reference)
//
#include <hip/hip_runtime.h>
#include <hip/hip_bf16.h>

typedef int   i32x4 __attribute__((ext_vector_type(4)));

#define N_IMG 64
#define CIN   256
#define COUT  256
#define HH    28
#define WW    28
#define PH    30
#define PW    30
#define M_TOT (N_IMG*HH*WW)          // 50176
#define OUT_ELEMS (N_IMG*COUT*HH*WW) // 12845056

// workspace layout (bytes) — all int8
#define XT_BYTES   ((size_t)N_IMG*PH*PW*CIN)       // 14745600
#define WT_OFF     (XT_BYTES)
#define WT_BYTES   ((size_t)9*COUT*CIN)            // 589824
#define BQ_OFF     (WT_OFF + WT_BYTES)             // 15335424

#define GLD16(g, l) __builtin_amdgcn_global_load_lds( \
    (const __attribute__((address_space(1))) void*)(g), \
    (__attribute__((address_space(3))) void*)(l), 16, 0, 0)

// ---------------------------------------------------------------------------
// Kernel 1: x int32 NCHW -> padded int8 NHWC [N][30][30][256], value x-127,
// PAD = -127  (so conv_i8 + 127*sum(w) == true conv with zero-padding).
__global__ __launch_bounds__(256) void transform_x(const int* __restrict__ xq,
                                                   signed char* __restrict__ xt) {
    __shared__ int xs[CIN*29];     // padded stride 29 -> no bank conflicts
    const int b = blockIdx.x;
    const int n = b / PH, py = b % PH;
    const int t = threadIdx.x;
    signed char* dst = xt + ((size_t)(n*PH + py))*PW*CIN;
    if (py == 0 || py == PH-1) {
        for (int i = t; i < PW*CIN; i += 256) dst[i] = -127;
        return;
    }
    const int h = py - 1;
    const int* src = xq + (size_t)n*CIN*HH*WW + h*WW;
    for (int i = t; i < CIN*WW; i += 256) {
        const int ci = i / WW, w = i % WW;
        xs[ci*29 + w] = src[ci*HH*WW + w];
    }
    __syncthreads();
    for (int i = t; i < PW*CIN; i += 256) {
        const int px = i / CIN, ci = i % CIN;
        const int v = (px == 0 || px == PW-1) ? 0 : xs[ci*29 + (px-1)];
        dst[px*CIN + ci] = (signed char)(v - 127);
    }
}

// ---------------------------------------------------------------------------
// Kernel 2: per-channel weight quant (int8) + bias quant + scale_out.
// wt layout: [tap(9)][co(256)][ci(256)] int8.  bq[co] folds in the +127*S
// correction for the x-shift (S = sum of all w_q for channel co).
__global__ __launch_bounds__(256) void quant_w(const float* __restrict__ weight,
                                               const float* __restrict__ scale_x,
                                               const float* __restrict__ bias,
                                               signed char* __restrict__ wt,
                                               int* __restrict__ bq,
                                               float* __restrict__ out_tail) {
    __shared__ float red[256];
    __shared__ int  sred[256];
    const int co = blockIdx.x, t = threadIdx.x;
    const float* wrow = weight + (size_t)co*CIN*9;
    float wv[9];
    float mx = 0.f;
    for (int it = 0; it < 9; ++it) {
        float v = wrow[it*256 + t];
        wv[it] = v;
        mx = fmaxf(mx, fabsf(v));
    }
    red[t] = mx;
    __syncthreads();
    for (int s = 128; s > 0; s >>= 1) {
        if (t < s) red[t] = fmaxf(red[t], red[t+s]);
        __syncthreads();
    }
    const float scale = fmaxf(red[0], 1e-8f) / 127.f;
    int isum = 0;
    for (int it = 0; it < 9; ++it) {
        const int i = it*256 + t;          // index over [ci][r][s]
        const int ci = i / 9, rs = i % 9;
        float q = rintf(wv[it] / scale);   // rintf = round-half-even = jnp.round
        q = fminf(fmaxf(q, -128.f), 127.f);
        const int qi = (int)q;
        isum += qi;
        wt[(size_t)rs*COUT*CIN + co*CIN + ci] = (signed char)qi;
    }
    sred[t] = isum;
    __syncthreads();
    for (int s = 128; s > 0; s >>= 1) {
        if (t < s) sred[t] += sred[t+s];
        __syncthreads();
    }
    if (t == 0) {
        const float so = scale * scale_x[0];
        out_tail[co] = so;
        bq[co] = (int)rintf(bias[co] / so) + 127 * sred[0];
    }
}

// ---------------------------------------------------------------------------
// Kernel 3: implicit-GEMM conv, int8 MFMA, m97-regime TLP configuration.
// BM=128 x BN=128 x BK=64, 256 thr / 4 waves (2 co x 2 m), per-wave 64x64 =
// acc[4][4], 16 MFMA + 8 ds_read_b128 per K-tile per wave. 36 K-tiles.
// LDS: 2 buffers x (A 8KB + B 8KB) = 32KB -> up to 5 blocks/CU; grid
// 392x2 = 784 blocks (~3 blocks/CU). Independent barrier groups overlap
// (m114): another block's MFMAs cover this block's vmcnt(0) drain —
// TLP instead of intra-block pipelining (which lost 3x: R7/R8/R10).
// Chunked LDS [kc(4)][row(128)][16B]: linear for global_load_lds, 0 bank
// conflicts (measured).  Schedule = R6/R9 winner.
// XCD swizzle: grid.x = 392 m-tiles = 8 x 49 (BIJECTIVE: mb=(bx&7)*49+bx>>3;
// R12's *98 variant overflowed m0 -> OOB writes -> core dump). Each XCD's 49
// consecutive m-tiles = 8 images ~ 1.84MB of xt -> 9-tap reuse is L2-local.
__global__ __launch_bounds__(256, 4) void conv_mfma(const signed char* __restrict__ xt,
                                                    const signed char* __restrict__ wt,
                                                    const int* __restrict__ bq,
                                                    float* __restrict__ out) {
    __shared__ signed char Ash[2*8192];   // [buf][kc4][row128][16]
    __shared__ signed char Bsh[2*8192];
    const int d = threadIdx.x;
    const int w4 = d >> 6;                   // wave id 0..3
    const int lane = d & 63, lr = lane & 15, kg = lane >> 4;
    const int wm = w4 >> 1, wn = w4 & 1;     // wave grid: 2 (co) x 2 (m)
    const int bx = blockIdx.x;               // 0..391
    const int mb = (bx & 7)*49 + (bx >> 3);  // bijective XCD swizzle (392=8*49)
    const int m0 = mb << 7;
    const int co0 = blockIdx.y << 7;

    // staging: thread d -> row d&127, kc (d>>7) and (d>>7)+2 (2 loads each op)
    const signed char* aS = wt + (size_t)(co0 + (d & 127))*CIN + ((d >> 7) << 4);
    const signed char* bS;
    {
        const int m = m0 + (d & 127);
        const int n = m / 784, hw = m % 784, h = hw / 28, wq = hw % 28;
        bS = xt + ((size_t)((n*PH + h)*PW + wq))*CIN + ((d >> 7) << 4);
    }
    const int dstw = w4 << 10;               // wave-uniform LDS byte base

    i32x4 acc[4][4] = {};

    // frag read byte bases: kc(=kg)*2048 + row*16
    const int arb = kg*2048 + (wm*64 + lr)*16;
    const int brb = kg*2048 + (wn*64 + lr)*16;

#define STAGE(T_, P_) do { \
    const int tap_ = (T_) >> 2, c_ = (T_) & 3; \
    const int r3_ = (tap_*171) >> 9; \
    const int ao_ = tap_*(COUT*CIN) + (c_ << 6); \
    const int bo_ = ((r3_*PW + (tap_ - r3_*3)) << 8) + (c_ << 6); \
    GLD16(aS + ao_,      Ash + (P_)*8192 + dstw); \
    GLD16(aS + ao_ + 32, Ash + (P_)*8192 + 4096 + dstw); \
    GLD16(bS + bo_,      Bsh + (P_)*8192 + dstw); \
    GLD16(bS + bo_ + 32, Bsh + (P_)*8192 + 4096 + dstw); \
} while (0)

#define COMPUTE(P_) do { \
    const signed char* A_ = Ash + (P_)*8192; \
    const signed char* B_ = Bsh + (P_)*8192; \
    i32x4 af[4], bf[4]; \
    _Pragma("unroll") \
    for (int mr = 0; mr < 4; ++mr) af[mr] = *(const i32x4*)&A_[arb + mr*256]; \
    _Pragma("unroll") \
    for (int nr = 0; nr < 4; ++nr) bf[nr] = *(const i32x4*)&B_[brb + nr*256]; \
    _Pragma("unroll") \
    for (int mr = 0; mr < 4; ++mr) \
        _Pragma("unroll") \
        for (int nr = 0; nr < 4; ++nr) \
            acc[mr][nr] = __builtin_amdgcn_mfma_i32_16x16x64_i8( \
                af[mr], bf[nr], acc[mr][nr], 0, 0, 0); \
} while (0)

#define SYNCPT() do { \
    asm volatile("s_waitcnt vmcnt(0) lgkmcnt(0)" ::: "memory"); \
    __builtin_amdgcn_s_barrier(); \
    __builtin_amdgcn_sched_barrier(0); \
} while (0)

    STAGE(0, 0);
#pragma unroll 1
    for (int tt = 0; tt < 36; tt += 2) {
        SYNCPT();                       // tile tt landed
        STAGE(tt + 1, 1);               // prefetch next into spare buffer
        COMPUTE(0);                     // tile tt
        SYNCPT();                       // tile tt+1 landed
        if (tt < 34) STAGE(tt + 2, 0);
        COMPUTE(1);                     // tile tt+1
    }

    // epilogue: D row = co (kg*4+rg), col = m (lr); 64B coalesced runs
#pragma unroll
    for (int nr = 0; nr < 4; ++nr) {
        const int mm = m0 + wn*64 + nr*16 + lr;
        const int nn = mm / 784, hw2 = mm % 784;
        float* orow = out + (size_t)nn*COUT*784 + hw2;
#pragma unroll
        for (int mr = 0; mr < 4; ++mr) {
            const int co = co0 + wm*64 + mr*16 + kg*4;
#pragma unroll
            for (int rg = 0; rg < 4; ++rg)
                orow[(size_t)(co + rg)*784] = (float)(acc[mr][nr][rg] + bq[co + rg]);
        }
    }
#undef STAGE
#undef COMPUTE
#undef SYNCPT
}

// ---------------------------------------------------------------------------
extern "C" void kernel_launch(void* const* d_in, const int* in_sizes, int n_in,
                              void* d_out, int out_size, void* d_ws, size_t ws_size,
                              hipStream_t stream) {
    const int*   xq      = (const int*)d_in[0];
    const float* scale_x = (const float*)d_in[1];
    const float* weight  = (const float*)d_in[2];
    const float* bias    = (const float*)d_in[3];
    float* out = (float*)d_out;

    signed char* xt = (signed char*)d_ws;
    signed char* wt = (signed char*)((char*)d_ws + WT_OFF);
    int*         bq = (int*)((char*)d_ws + BQ_OFF);

    hipLaunchKernelGGL(transform_x, dim3(N_IMG*PH), dim3(256), 0, stream, xq, xt);
    hipLaunchKernelGGL(quant_w, dim3(COUT), dim3(256), 0, stream,
                       weight, scale_x, bias, wt, bq, out + OUT_ELEMS);
    hipLaunchKernelGGL(conv_mfma, dim3(M_TOT/128, COUT/128), dim3(256), 0, stream,
                       xt, wt, bq, out);
}

// Round 14
// 108.369 us; speedup vs baseline: 1.0176x; 1.0176x over previous
//
#include <hip/hip_runtime.h>
#include <hip/hip_bf16.h>

typedef int   i32x4 __attribute__((ext_vector_type(4)));

#define N_IMG 64
#define CIN   256
#define COUT  256
#define HH    28
#define WW    28
#define PH    30
#define PW    30
#define M_TOT (N_IMG*HH*WW)          // 50176
#define OUT_ELEMS (N_IMG*COUT*HH*WW) // 12845056

// workspace layout (bytes) — all int8
#define XT_BYTES   ((size_t)N_IMG*PH*PW*CIN)       // 14745600
#define WT_OFF     (XT_BYTES)
#define WT_BYTES   ((size_t)9*COUT*CIN)            // 589824
#define BQ_OFF     (WT_OFF + WT_BYTES)             // 15335424

#define GLD16(g, l) __builtin_amdgcn_global_load_lds( \
    (const __attribute__((address_space(1))) void*)(g), \
    (__attribute__((address_space(3))) void*)(l), 16, 0, 0)

// ---------------------------------------------------------------------------
// Kernel 1: x int32 NCHW -> padded int8 NHWC [N][30][30][256], value x-127,
// PAD = -127  (so conv_i8 + 127*sum(w) == true conv with zero-padding).
__global__ __launch_bounds__(256) void transform_x(const int* __restrict__ xq,
                                                   signed char* __restrict__ xt) {
    __shared__ int xs[CIN*29];     // padded stride 29 -> no bank conflicts
    const int b = blockIdx.x;
    const int n = b / PH, py = b % PH;
    const int t = threadIdx.x;
    signed char* dst = xt + ((size_t)(n*PH + py))*PW*CIN;
    if (py == 0 || py == PH-1) {
        for (int i = t; i < PW*CIN; i += 256) dst[i] = -127;
        return;
    }
    const int h = py - 1;
    const int* src = xq + (size_t)n*CIN*HH*WW + h*WW;
    for (int i = t; i < CIN*WW; i += 256) {
        const int ci = i / WW, w = i % WW;
        xs[ci*29 + w] = src[ci*HH*WW + w];
    }
    __syncthreads();
    for (int i = t; i < PW*CIN; i += 256) {
        const int px = i / CIN, ci = i % CIN;
        const int v = (px == 0 || px == PW-1) ? 0 : xs[ci*29 + (px-1)];
        dst[px*CIN + ci] = (signed char)(v - 127);
    }
}

// ---------------------------------------------------------------------------
// Kernel 2: per-channel weight quant (int8) + bias quant + scale_out.
// wt layout: [tap(9)][co(256)][ci(256)] int8.  bq[co] folds in the +127*S
// correction for the x-shift (S = sum of all w_q for channel co).
__global__ __launch_bounds__(256) void quant_w(const float* __restrict__ weight,
                                               const float* __restrict__ scale_x,
                                               const float* __restrict__ bias,
                                               signed char* __restrict__ wt,
                                               int* __restrict__ bq,
                                               float* __restrict__ out_tail) {
    __shared__ float red[256];
    __shared__ int  sred[256];
    const int co = blockIdx.x, t = threadIdx.x;
    const float* wrow = weight + (size_t)co*CIN*9;
    float wv[9];
    float mx = 0.f;
    for (int it = 0; it < 9; ++it) {
        float v = wrow[it*256 + t];
        wv[it] = v;
        mx = fmaxf(mx, fabsf(v));
    }
    red[t] = mx;
    __syncthreads();
    for (int s = 128; s > 0; s >>= 1) {
        if (t < s) red[t] = fmaxf(red[t], red[t+s]);
        __syncthreads();
    }
    const float scale = fmaxf(red[0], 1e-8f) / 127.f;
    int isum = 0;
    for (int it = 0; it < 9; ++it) {
        const int i = it*256 + t;          // index over [ci][r][s]
        const int ci = i / 9, rs = i % 9;
        float q = rintf(wv[it] / scale);   // rintf = round-half-even = jnp.round
        q = fminf(fmaxf(q, -128.f), 127.f);
        const int qi = (int)q;
        isum += qi;
        wt[(size_t)rs*COUT*CIN + co*CIN + ci] = (signed char)qi;
    }
    sred[t] = isum;
    __syncthreads();
    for (int s = 128; s > 0; s >>= 1) {
        if (t < s) sred[t] += sred[t+s];
        __syncthreads();
    }
    if (t == 0) {
        const float so = scale * scale_x[0];
        out_tail[co] = so;
        bq[co] = (int)rintf(bias[co] / so) + 127 * sred[0];
    }
}

// ---------------------------------------------------------------------------
// Kernel 3: implicit-GEMM conv, int8 MFMA, BK=128 drain-minimized.
// BM=256 (all co) x BN=128 x BK=128, 512 thr / 8 waves (4 co x 2 m), per-wave
// 64x64 = acc[4][4]; per K-tile per wave: 32 MFMA (2 k-steps) + 16 ds_read.
// ONLY 18 K-tiles (9 taps x 2 ci-halves) -> 18 drain points (was 36 in R9,
// whose per-tile ~900cy vmcnt(0) drain is the measured dominant stall;
// R7/R8/R10 counted-vmcnt and R13 TLP both failed to hide it -- so cut its
// COUNT instead).  LDS: 2 x (A 32KB + B 16KB) = 96KB -> 1 block/CU (measured
// occupancy was ~1 block anyway; m132's BK=128 loss was occupancy-driven,
// not applicable here).  Chunked [kc(8)][row][16B] layout: linear for
// global_load_lds, same bank pattern that measured 0 conflicts (R9/R13).
// Schedule = R6/R9 winner.  Bijective XCD swizzle (392 = 8 x 49): each XCD's
// 49 consecutive m-tiles = ~1.84MB xt -> 9-tap reuse L2-local.
__global__ __launch_bounds__(512, 1) void conv_mfma(const signed char* __restrict__ xt,
                                                    const signed char* __restrict__ wt,
                                                    const int* __restrict__ bq,
                                                    float* __restrict__ out) {
    __shared__ signed char Ash[2*32768];  // [buf][kc8][row256][16]
    __shared__ signed char Bsh[2*16384];  // [buf][kc8][row128][16]
    const int d = threadIdx.x;
    const int w8 = d >> 6;                   // wave id 0..7
    const int lane = d & 63, lr = lane & 15, kg = lane >> 4;
    const int wm = w8 >> 1, wn = w8 & 1;     // wave grid: 4 (co) x 2 (m)
    const int bx = blockIdx.x;               // 0..391
    const int mb = (bx & 7)*49 + (bx >> 3);  // bijective XCD swizzle (392=8*49)
    const int m0 = mb << 7;

    // staging sources
    //   A: thread d -> row d&255, kc = j*2 + (d>>8), j = 0..3   (4 loads)
    //   B: thread d -> row d&127, kc = j*4 + (d>>7), j = 0..1   (2 loads)
    const signed char* aS = wt + (size_t)(d & 255)*CIN + ((d >> 8) << 4);
    const signed char* bS;
    {
        const int m = m0 + (d & 127);
        const int n = m / 784, hw = m % 784, h = hw / 28, wq = hw % 28;
        bS = xt + ((size_t)((n*PH + h)*PW + wq))*CIN + ((d >> 7) << 4);
    }
    const int dstb = d << 4;                 // linear LDS dest = d*16 + j*8192

    i32x4 acc[4][4] = {};

    // frag read byte bases (+= ks*{16384,8192} per k-step, += {mr,nr}*256)
    const int arb = kg*4096 + (wm*64 + lr)*16;
    const int brb = kg*2048 + (wn*64 + lr)*16;

#define STAGE(T_, P_) do { \
    const int tap_ = (T_) >> 1, c_ = (T_) & 1; \
    const int r3_ = (tap_*171) >> 9; \
    const int ao_ = tap_*(COUT*CIN) + (c_ << 7); \
    const int bo_ = ((r3_*PW + (tap_ - r3_*3)) << 8) + (c_ << 7); \
    GLD16(aS + ao_,       Ash + (P_)*32768 + dstb); \
    GLD16(aS + ao_ + 32,  Ash + (P_)*32768 + 8192 + dstb); \
    GLD16(aS + ao_ + 64,  Ash + (P_)*32768 + 16384 + dstb); \
    GLD16(aS + ao_ + 96,  Ash + (P_)*32768 + 24576 + dstb); \
    GLD16(bS + bo_,       Bsh + (P_)*16384 + dstb); \
    GLD16(bS + bo_ + 64,  Bsh + (P_)*16384 + 8192 + dstb); \
} while (0)

#define COMPUTE(P_) do { \
    const signed char* A_ = Ash + (P_)*32768; \
    const signed char* B_ = Bsh + (P_)*16384; \
    _Pragma("unroll") \
    for (int ks = 0; ks < 2; ++ks) { \
        i32x4 af[4], bf[4]; \
        _Pragma("unroll") \
        for (int mr = 0; mr < 4; ++mr) \
            af[mr] = *(const i32x4*)&A_[arb + ks*16384 + mr*256]; \
        _Pragma("unroll") \
        for (int nr = 0; nr < 4; ++nr) \
            bf[nr] = *(const i32x4*)&B_[brb + ks*8192 + nr*256]; \
        _Pragma("unroll") \
        for (int mr = 0; mr < 4; ++mr) \
            _Pragma("unroll") \
            for (int nr = 0; nr < 4; ++nr) \
                acc[mr][nr] = __builtin_amdgcn_mfma_i32_16x16x64_i8( \
                    af[mr], bf[nr], acc[mr][nr], 0, 0, 0); \
    } \
} while (0)

#define SYNCPT() do { \
    asm volatile("s_waitcnt vmcnt(0) lgkmcnt(0)" ::: "memory"); \
    __builtin_amdgcn_s_barrier(); \
    __builtin_amdgcn_sched_barrier(0); \
} while (0)

    STAGE(0, 0);
#pragma unroll 1
    for (int tt = 0; tt < 18; tt += 2) {
        SYNCPT();                       // tile tt landed
        STAGE(tt + 1, 1);               // prefetch next into spare buffer
        COMPUTE(0);                     // tile tt
        SYNCPT();                       // tile tt+1 landed
        if (tt < 16) STAGE(tt + 2, 0);
        COMPUTE(1);                     // tile tt+1
    }

    // epilogue: D row = co (kg*4+rg), col = m (lr); 64B coalesced runs
#pragma unroll
    for (int nr = 0; nr < 4; ++nr) {
        const int mm = m0 + wn*64 + nr*16 + lr;
        const int nn = mm / 784, hw2 = mm % 784;
        float* orow = out + (size_t)nn*COUT*784 + hw2;
#pragma unroll
        for (int mr = 0; mr < 4; ++mr) {
            const int co = wm*64 + mr*16 + kg*4;
#pragma unroll
            for (int rg = 0; rg < 4; ++rg)
                orow[(size_t)(co + rg)*784] = (float)(acc[mr][nr][rg] + bq[co + rg]);
        }
    }
#undef STAGE
#undef COMPUTE
#undef SYNCPT
}

// ---------------------------------------------------------------------------
extern "C" void kernel_launch(void* const* d_in, const int* in_sizes, int n_in,
                              void* d_out, int out_size, void* d_ws, size_t ws_size,
                              hipStream_t stream) {
    const int*   xq      = (const int*)d_in[0];
    const float* scale_x = (const float*)d_in[1];
    const float* weight  = (const float*)d_in[2];
    const float* bias    = (const float*)d_in[3];
    float* out = (float*)d_out;

    signed char* xt = (signed char*)d_ws;
    signed char* wt = (signed char*)((char*)d_ws + WT_OFF);
    int*         bq = (int*)((char*)d_ws + BQ_OFF);

    hipLaunchKernelGGL(transform_x, dim3(N_IMG*PH), dim3(256), 0, stream, xq, xt);
    hipLaunchKernelGGL(quant_w, dim3(COUT), dim3(256), 0, stream,
                       weight, scale_x, bias, wt, bq, out + OUT_ELEMS);
    hipLaunchKernelGGL(conv_mfma, dim3(M_TOT/128), dim3(512), 0, stream,
                       xt, wt, bq, out);
}

// Round 15
// 76.165 us; speedup vs baseline: 1.4479x; 1.4228x over previous
//
#include <hip/hip_runtime.h>
#include <hip/hip_bf16.h>

typedef int   i32x4 __attribute__((ext_vector_type(4)));

#define N_IMG 64
#define CIN   256
#define COUT  256
#define HH    28
#define WW    28
#define PH    30
#define PW    30
#define M_TOT (N_IMG*HH*WW)          // 50176
#define OUT_ELEMS (N_IMG*COUT*HH*WW) // 12845056

// workspace layout (bytes) — all int8
#define XT_BYTES   ((size_t)N_IMG*PH*PW*CIN)       // 14745600
#define WT_OFF     (XT_BYTES)
#define WT_BYTES   ((size_t)9*COUT*CIN)            // 589824
#define BQ_OFF     (WT_OFF + WT_BYTES)             // 15335424

#define GLD16(g, l) __builtin_amdgcn_global_load_lds( \
    (const __attribute__((address_space(1))) void*)(g), \
    (__attribute__((address_space(3))) void*)(l), 16, 0, 0)

// ---------------------------------------------------------------------------
// Kernel 1: x int32 NCHW -> padded int8 NHWC [N][30][30][256], value x-127,
// PAD = -127  (so conv_i8 + 127*sum(w) == true conv with zero-padding).
__global__ __launch_bounds__(256) void transform_x(const int* __restrict__ xq,
                                                   signed char* __restrict__ xt) {
    __shared__ int xs[CIN*29];     // padded stride 29 -> no bank conflicts
    const int b = blockIdx.x;
    const int n = b / PH, py = b % PH;
    const int t = threadIdx.x;
    signed char* dst = xt + ((size_t)(n*PH + py))*PW*CIN;
    if (py == 0 || py == PH-1) {
        for (int i = t; i < PW*CIN; i += 256) dst[i] = -127;
        return;
    }
    const int h = py - 1;
    const int* src = xq + (size_t)n*CIN*HH*WW + h*WW;
    for (int i = t; i < CIN*WW; i += 256) {
        const int ci = i / WW, w = i % WW;
        xs[ci*29 + w] = src[ci*HH*WW + w];
    }
    __syncthreads();
    for (int i = t; i < PW*CIN; i += 256) {
        const int px = i / CIN, ci = i % CIN;
        const int v = (px == 0 || px == PW-1) ? 0 : xs[ci*29 + (px-1)];
        dst[px*CIN + ci] = (signed char)(v - 127);
    }
}

// ---------------------------------------------------------------------------
// Kernel 2: per-channel weight quant (int8) + bias quant + scale_out.
// wt layout: [tap(9)][co(256)][ci(256)] int8.  bq[co] folds in the +127*S
// correction for the x-shift (S = sum of all w_q for channel co).
__global__ __launch_bounds__(256) void quant_w(const float* __restrict__ weight,
                                               const float* __restrict__ scale_x,
                                               const float* __restrict__ bias,
                                               signed char* __restrict__ wt,
                                               int* __restrict__ bq,
                                               float* __restrict__ out_tail) {
    __shared__ float red[256];
    __shared__ int  sred[256];
    const int co = blockIdx.x, t = threadIdx.x;
    const float* wrow = weight + (size_t)co*CIN*9;
    float wv[9];
    float mx = 0.f;
    for (int it = 0; it < 9; ++it) {
        float v = wrow[it*256 + t];
        wv[it] = v;
        mx = fmaxf(mx, fabsf(v));
    }
    red[t] = mx;
    __syncthreads();
    for (int s = 128; s > 0; s >>= 1) {
        if (t < s) red[t] = fmaxf(red[t], red[t+s]);
        __syncthreads();
    }
    const float scale = fmaxf(red[0], 1e-8f) / 127.f;
    int isum = 0;
    for (int it = 0; it < 9; ++it) {
        const int i = it*256 + t;          // index over [ci][r][s]
        const int ci = i / 9, rs = i % 9;
        float q = rintf(wv[it] / scale);   // rintf = round-half-even = jnp.round
        q = fminf(fmaxf(q, -128.f), 127.f);
        const int qi = (int)q;
        isum += qi;
        wt[(size_t)rs*COUT*CIN + co*CIN + ci] = (signed char)qi;
    }
    sred[t] = isum;
    __syncthreads();
    for (int s = 128; s > 0; s >>= 1) {
        if (t < s) sred[t] += sred[t+s];
        __syncthreads();
    }
    if (t == 0) {
        const float so = scale * scale_x[0];
        out_tail[co] = so;
        bq[co] = (int)rintf(bias[co] / so) + 127 * sred[0];
    }
}

// ---------------------------------------------------------------------------
// Kernel 3: implicit-GEMM conv, int8 MFMA, BK=128, COALESCED staging + T2
// XOR-swizzle (pre-swizzled GLOBAL source, linear LDS dest, swizzled read —
// rule #21's both-sides pattern).
//   Staging: 8 lanes/row x 16B = contiguous 128B per row (fully coalesced;
//   R9-R14's 16B-scattered staging was ~4x TA/L2-transaction inflated = the
//   measured schedule-independent ~80us floor).  Lane d loads k-chunk
//   kc = (d&7)^((d>>3)&7) so linear dest yields XOR-swizzled [row][128B];
//   frag ds_read uses addr = row*128 + ((kg^(lr&7))<<4)^(ks<<6) -> uniform
//   8 lanes/bank-quad (conflict-free for b128).
// Geometry = R14: BM=256 x BN=128 x BK=128, 512 thr / 8 waves (4co x 2m),
// per-wave 64x64 acc[4][4], 32 MFMA + 16 ds_read per tile, 18 K-tiles.
// LDS 2 x (A 32KB + B 16KB) = 96KB.  Schedule = R6/R9 2-phase winner.
// Bijective XCD swizzle (392 = 8x49) keeps xt 9-tap reuse L2-local.
__global__ __launch_bounds__(512, 1) void conv_mfma(const signed char* __restrict__ xt,
                                                    const signed char* __restrict__ wt,
                                                    const int* __restrict__ bq,
                                                    float* __restrict__ out) {
    __shared__ signed char Ash[2*32768];  // [buf][row256][128B] XOR-swizzled
    __shared__ signed char Bsh[2*16384];  // [buf][row128][128B] XOR-swizzled
    const int d = threadIdx.x;
    const int w8 = d >> 6;                   // wave id 0..7
    const int lane = d & 63, lr = lane & 15, kg = lane >> 4;
    const int wm = w8 >> 1, wn = w8 & 1;     // wave grid: 4 (co) x 2 (m)
    const int bx = blockIdx.x;               // 0..391
    const int mb = (bx & 7)*49 + (bx >> 3);  // bijective XCD swizzle (392=8*49)
    const int m0 = mb << 7;

    // coalesced + pre-swizzled staging sources: lane covers row srow (+j*64),
    // k-chunk kc = (d&7)^(srow&7)  (XOR involution; 8 lanes permute one 128B run)
    const int srow = d >> 3;                 // 0..63
    const int skc  = (d & 7) ^ (srow & 7);
    const signed char* aS = wt + srow*CIN + (skc << 4);   // + j*16384 + tap*65536 + c*128
    const signed char* bS0;
    const signed char* bS1;
    {
        int m = m0 + srow;
        int n = m / 784, hw = m % 784, h = hw / 28, wq = hw % 28;
        bS0 = xt + ((size_t)((n*PH + h)*PW + wq))*CIN + (skc << 4);
        m += 64;
        n = m / 784; hw = m % 784; h = hw / 28; wq = hw % 28;
        bS1 = xt + ((size_t)((n*PH + h)*PW + wq))*CIN + (skc << 4);
    }
    const int w8off = w8 << 10;              // wave-uniform LDS base (bytes)

    i32x4 acc[4][4] = {};

    // frag read byte bases (XOR-swizzled); ks=1 flips bit 6
    const int a0 = (wm*64 + lr)*128 + ((kg ^ (lr & 7)) << 4);
    const int b0 = (wn*64 + lr)*128 + ((kg ^ (lr & 7)) << 4);

#define STAGE(T_, P_) do { \
    const int tap_ = (T_) >> 1, c_ = (T_) & 1; \
    const int r3_ = (tap_*171) >> 9; \
    const int ao_ = tap_*(COUT*CIN) + (c_ << 7); \
    const int bo_ = ((r3_*PW + (tap_ - r3_*3)) << 8) + (c_ << 7); \
    GLD16(aS + ao_,         Ash + (P_)*32768 +         w8off); \
    GLD16(aS + ao_ + 16384, Ash + (P_)*32768 +  8192 + w8off); \
    GLD16(aS + ao_ + 32768, Ash + (P_)*32768 + 16384 + w8off); \
    GLD16(aS + ao_ + 49152, Ash + (P_)*32768 + 24576 + w8off); \
    GLD16(bS0 + bo_,        Bsh + (P_)*16384 +         w8off); \
    GLD16(bS1 + bo_,        Bsh + (P_)*16384 +  8192 + w8off); \
} while (0)

#define COMPUTE(P_) do { \
    const signed char* A_ = Ash + (P_)*32768; \
    const signed char* B_ = Bsh + (P_)*16384; \
    _Pragma("unroll") \
    for (int ks = 0; ks < 2; ++ks) { \
        const int ar = a0 ^ (ks << 6); \
        const int br = b0 ^ (ks << 6); \
        i32x4 af[4], bf[4]; \
        _Pragma("unroll") \
        for (int mr = 0; mr < 4; ++mr) \
            af[mr] = *(const i32x4*)&A_[ar + mr*2048]; \
        _Pragma("unroll") \
        for (int nr = 0; nr < 4; ++nr) \
            bf[nr] = *(const i32x4*)&B_[br + nr*2048]; \
        _Pragma("unroll") \
        for (int mr = 0; mr < 4; ++mr) \
            _Pragma("unroll") \
            for (int nr = 0; nr < 4; ++nr) \
                acc[mr][nr] = __builtin_amdgcn_mfma_i32_16x16x64_i8( \
                    af[mr], bf[nr], acc[mr][nr], 0, 0, 0); \
    } \
} while (0)

#define SYNCPT() do { \
    asm volatile("s_waitcnt vmcnt(0) lgkmcnt(0)" ::: "memory"); \
    __builtin_amdgcn_s_barrier(); \
    __builtin_amdgcn_sched_barrier(0); \
} while (0)

    STAGE(0, 0);
#pragma unroll 1
    for (int tt = 0; tt < 18; tt += 2) {
        SYNCPT();                       // tile tt landed
        STAGE(tt + 1, 1);               // prefetch next into spare buffer
        COMPUTE(0);                     // tile tt
        SYNCPT();                       // tile tt+1 landed
        if (tt < 16) STAGE(tt + 2, 0);
        COMPUTE(1);                     // tile tt+1
    }

    // epilogue: D row = co (kg*4+rg), col = m (lr); 64B coalesced runs
#pragma unroll
    for (int nr = 0; nr < 4; ++nr) {
        const int mm = m0 + wn*64 + nr*16 + lr;
        const int nn = mm / 784, hw2 = mm % 784;
        float* orow = out + (size_t)nn*COUT*784 + hw2;
#pragma unroll
        for (int mr = 0; mr < 4; ++mr) {
            const int co = wm*64 + mr*16 + kg*4;
#pragma unroll
            for (int rg = 0; rg < 4; ++rg)
                orow[(size_t)(co + rg)*784] = (float)(acc[mr][nr][rg] + bq[co + rg]);
        }
    }
#undef STAGE
#undef COMPUTE
#undef SYNCPT
}

// ---------------------------------------------------------------------------
extern "C" void kernel_launch(void* const* d_in, const int* in_sizes, int n_in,
                              void* d_out, int out_size, void* d_ws, size_t ws_size,
                              hipStream_t stream) {
    const int*   xq      = (const int*)d_in[0];
    const float* scale_x = (const float*)d_in[1];
    const float* weight  = (const float*)d_in[2];
    const float* bias    = (const float*)d_in[3];
    float* out = (float*)d_out;

    signed char* xt = (signed char*)d_ws;
    signed char* wt = (signed char*)((char*)d_ws + WT_OFF);
    int*         bq = (int*)((char*)d_ws + BQ_OFF);

    hipLaunchKernelGGL(transform_x, dim3(N_IMG*PH), dim3(256), 0, stream, xq, xt);
    hipLaunchKernelGGL(quant_w, dim3(COUT), dim3(256), 0, stream,
                       weight, scale_x, bias, wt, bq, out + OUT_ELEMS);
    hipLaunchKernelGGL(conv_mfma, dim3(M_TOT/128), dim3(512), 0, stream,
                       xt, wt, bq, out);
}

// Round 16
// 73.133 us; speedup vs baseline: 1.5079x; 1.0415x over previous
//
#include <hip/hip_runtime.h>
#include <hip/hip_bf16.h>

typedef int   i32x4 __attribute__((ext_vector_type(4)));

#define N_IMG 64
#define CIN   256
#define COUT  256
#define HH    28
#define WW    28
#define PH    30
#define PW    30
#define M_TOT (N_IMG*HH*WW)          // 50176
#define OUT_ELEMS (N_IMG*COUT*HH*WW) // 12845056

// workspace layout (bytes) — all int8
#define XT_BYTES   ((size_t)N_IMG*PH*PW*CIN)       // 14745600
#define WT_OFF     (XT_BYTES)
#define WT_BYTES   ((size_t)9*COUT*CIN)            // 589824
#define BQ_OFF     (WT_OFF + WT_BYTES)             // 15335424

#define GLD16(g, l) __builtin_amdgcn_global_load_lds( \
    (const __attribute__((address_space(1))) void*)(g), \
    (__attribute__((address_space(3))) void*)(l), 16, 0, 0)

// ---------------------------------------------------------------------------
// Kernel 1: x int32 NCHW -> padded int8 NHWC [N][30][30][256], value x-127,
// PAD = -127  (so conv_i8 + 127*sum(w) == true conv with zero-padding).
__global__ __launch_bounds__(256) void transform_x(const int* __restrict__ xq,
                                                   signed char* __restrict__ xt) {
    __shared__ int xs[CIN*29];     // padded stride 29 -> no bank conflicts
    const int b = blockIdx.x;
    const int n = b / PH, py = b % PH;
    const int t = threadIdx.x;
    signed char* dst = xt + ((size_t)(n*PH + py))*PW*CIN;
    if (py == 0 || py == PH-1) {
        for (int i = t; i < PW*CIN; i += 256) dst[i] = -127;
        return;
    }
    const int h = py - 1;
    const int* src = xq + (size_t)n*CIN*HH*WW + h*WW;
    for (int i = t; i < CIN*WW; i += 256) {
        const int ci = i / WW, w = i % WW;
        xs[ci*29 + w] = src[ci*HH*WW + w];
    }
    __syncthreads();
    for (int i = t; i < PW*CIN; i += 256) {
        const int px = i / CIN, ci = i % CIN;
        const int v = (px == 0 || px == PW-1) ? 0 : xs[ci*29 + (px-1)];
        dst[px*CIN + ci] = (signed char)(v - 127);
    }
}

// ---------------------------------------------------------------------------
// Kernel 2: per-channel weight quant (int8) + bias quant + scale_out.
// wt layout: [tap(9)][co(256)][ci(256)] int8.  bq[co] folds in the +127*S
// correction for the x-shift (S = sum of all w_q for channel co).
__global__ __launch_bounds__(256) void quant_w(const float* __restrict__ weight,
                                               const float* __restrict__ scale_x,
                                               const float* __restrict__ bias,
                                               signed char* __restrict__ wt,
                                               int* __restrict__ bq,
                                               float* __restrict__ out_tail) {
    __shared__ float red[256];
    __shared__ int  sred[256];
    const int co = blockIdx.x, t = threadIdx.x;
    const float* wrow = weight + (size_t)co*CIN*9;
    float wv[9];
    float mx = 0.f;
    for (int it = 0; it < 9; ++it) {
        float v = wrow[it*256 + t];
        wv[it] = v;
        mx = fmaxf(mx, fabsf(v));
    }
    red[t] = mx;
    __syncthreads();
    for (int s = 128; s > 0; s >>= 1) {
        if (t < s) red[t] = fmaxf(red[t], red[t+s]);
        __syncthreads();
    }
    const float scale = fmaxf(red[0], 1e-8f) / 127.f;
    int isum = 0;
    for (int it = 0; it < 9; ++it) {
        const int i = it*256 + t;          // index over [ci][r][s]
        const int ci = i / 9, rs = i % 9;
        float q = rintf(wv[it] / scale);   // rintf = round-half-even = jnp.round
        q = fminf(fmaxf(q, -128.f), 127.f);
        const int qi = (int)q;
        isum += qi;
        wt[(size_t)rs*COUT*CIN + co*CIN + ci] = (signed char)qi;
    }
    sred[t] = isum;
    __syncthreads();
    for (int s = 128; s > 0; s >>= 1) {
        if (t < s) sred[t] += sred[t+s];
        __syncthreads();
    }
    if (t == 0) {
        const float so = scale * scale_x[0];
        out_tail[co] = so;
        bq[co] = (int)rintf(bias[co] / so) + 127 * sred[0];
    }
}

// ---------------------------------------------------------------------------
// Kernel 3: implicit-GEMM conv, int8 MFMA, R15 staging (coalesced 128B runs,
// pre-swizzled global source -> linear LDS dest -> XOR-swizzled ds_read;
// rule #21) at 2-BLOCK-PER-CU geometry.
// BM=128 (co-split, grid.y=2) x BN=128 x BK=128, 256 thr / 4 waves (2co x 2m),
// per-wave 64x64 acc[4][4], 32 MFMA + 16 ds_read_b128 per tile, 18 K-tiles.
// LDS: 2 bufs x (A 16KB + B 16KB) = 64KB -> 2 blocks co-resident/CU; grid
// 392x2 = 784 blocks (~3.06/CU): neighbor block's MFMAs cover this block's
// vmcnt(0) drain (m114) and the 1.53-block imbalance of R15 (96KB, 1/CU)
// disappears.  Both co-halves of an m-tile are 392 apart in linear block ID
// (392%8==0 -> same XCD) -> xt tile shared in that XCD's L2.
// Schedule = R6/R9 2-phase winner.  Bijective XCD swizzle (392 = 8x49).
__global__ __launch_bounds__(256, 2) void conv_mfma(const signed char* __restrict__ xt,
                                                    const signed char* __restrict__ wt,
                                                    const int* __restrict__ bq,
                                                    float* __restrict__ out) {
    __shared__ signed char Ash[2*16384];  // [buf][row128][128B] XOR-swizzled
    __shared__ signed char Bsh[2*16384];
    const int d = threadIdx.x;
    const int w4 = d >> 6;                   // wave id 0..3
    const int lane = d & 63, lr = lane & 15, kg = lane >> 4;
    const int wm = w4 >> 1, wn = w4 & 1;     // wave grid: 2 (co) x 2 (m)
    const int bx = blockIdx.x;               // 0..391
    const int mb = (bx & 7)*49 + (bx >> 3);  // bijective XCD swizzle (392=8*49)
    const int m0 = mb << 7;
    const int co0 = blockIdx.y << 7;

    // coalesced + pre-swizzled staging: 8 lanes/row x 16B = 128B run.
    // thread d covers row srow+j*32 (j=0..3); k-chunk kc = (d&7)^(srow&7)
    // (same for all j since j*32 keeps low 3 row bits).
    const int srow = d >> 3;                 // 0..31
    const int skc  = (d & 7) ^ (srow & 7);
    const signed char* aS = wt + (size_t)(co0 + srow)*CIN + (skc << 4); // +j*32*CIN
    const signed char* bS[4];
#pragma unroll
    for (int j = 0; j < 4; ++j) {
        const int m = m0 + srow + j*32;
        const int n = m / 784, hw = m % 784, h = hw / 28, wq = hw % 28;
        bS[j] = xt + ((size_t)((n*PH + h)*PW + wq))*CIN + (skc << 4);
    }
    const int w4off = w4 << 10;              // wave-uniform LDS base (bytes)

    i32x4 acc[4][4] = {};

    // frag read byte bases (XOR-swizzled); ks=1 flips bit 6
    const int a0 = (wm*64 + lr)*128 + ((kg ^ (lr & 7)) << 4);
    const int b0 = (wn*64 + lr)*128 + ((kg ^ (lr & 7)) << 4);

#define STAGE(T_, P_) do { \
    const int tap_ = (T_) >> 1, c_ = (T_) & 1; \
    const int r3_ = (tap_*171) >> 9; \
    const int ao_ = tap_*(COUT*CIN) + (c_ << 7); \
    const int bo_ = ((r3_*PW + (tap_ - r3_*3)) << 8) + (c_ << 7); \
    GLD16(aS + ao_,         Ash + (P_)*16384 +         w4off); \
    GLD16(aS + ao_ +  8192, Ash + (P_)*16384 +  4096 + w4off); \
    GLD16(aS + ao_ + 16384, Ash + (P_)*16384 +  8192 + w4off); \
    GLD16(aS + ao_ + 24576, Ash + (P_)*16384 + 12288 + w4off); \
    GLD16(bS[0] + bo_,      Bsh + (P_)*16384 +         w4off); \
    GLD16(bS[1] + bo_,      Bsh + (P_)*16384 +  4096 + w4off); \
    GLD16(bS[2] + bo_,      Bsh + (P_)*16384 +  8192 + w4off); \
    GLD16(bS[3] + bo_,      Bsh + (P_)*16384 + 12288 + w4off); \
} while (0)

#define COMPUTE(P_) do { \
    const signed char* A_ = Ash + (P_)*16384; \
    const signed char* B_ = Bsh + (P_)*16384; \
    _Pragma("unroll") \
    for (int ks = 0; ks < 2; ++ks) { \
        const int ar = a0 ^ (ks << 6); \
        const int br = b0 ^ (ks << 6); \
        i32x4 af[4], bf[4]; \
        _Pragma("unroll") \
        for (int mr = 0; mr < 4; ++mr) \
            af[mr] = *(const i32x4*)&A_[ar + mr*2048]; \
        _Pragma("unroll") \
        for (int nr = 0; nr < 4; ++nr) \
            bf[nr] = *(const i32x4*)&B_[br + nr*2048]; \
        _Pragma("unroll") \
        for (int mr = 0; mr < 4; ++mr) \
            _Pragma("unroll") \
            for (int nr = 0; nr < 4; ++nr) \
                acc[mr][nr] = __builtin_amdgcn_mfma_i32_16x16x64_i8( \
                    af[mr], bf[nr], acc[mr][nr], 0, 0, 0); \
    } \
} while (0)

#define SYNCPT() do { \
    asm volatile("s_waitcnt vmcnt(0) lgkmcnt(0)" ::: "memory"); \
    __builtin_amdgcn_s_barrier(); \
    __builtin_amdgcn_sched_barrier(0); \
} while (0)

    STAGE(0, 0);
#pragma unroll 1
    for (int tt = 0; tt < 18; tt += 2) {
        SYNCPT();                       // tile tt landed
        STAGE(tt + 1, 1);               // prefetch next into spare buffer
        COMPUTE(0);                     // tile tt
        SYNCPT();                       // tile tt+1 landed
        if (tt < 16) STAGE(tt + 2, 0);
        COMPUTE(1);                     // tile tt+1
    }

    // epilogue: D row = co (kg*4+rg), col = m (lr); 64B coalesced runs
#pragma unroll
    for (int nr = 0; nr < 4; ++nr) {
        const int mm = m0 + wn*64 + nr*16 + lr;
        const int nn = mm / 784, hw2 = mm % 784;
        float* orow = out + (size_t)nn*COUT*784 + hw2;
#pragma unroll
        for (int mr = 0; mr < 4; ++mr) {
            const int co = co0 + wm*64 + mr*16 + kg*4;
#pragma unroll
            for (int rg = 0; rg < 4; ++rg)
                orow[(size_t)(co + rg)*784] = (float)(acc[mr][nr][rg] + bq[co + rg]);
        }
    }
#undef STAGE
#undef COMPUTE
#undef SYNCPT
}

// ---------------------------------------------------------------------------
extern "C" void kernel_launch(void* const* d_in, const int* in_sizes, int n_in,
                              void* d_out, int out_size, void* d_ws, size_t ws_size,
                              hipStream_t stream) {
    const int*   xq      = (const int*)d_in[0];
    const float* scale_x = (const float*)d_in[1];
    const float* weight  = (const float*)d_in[2];
    const float* bias    = (const float*)d_in[3];
    float* out = (float*)d_out;

    signed char* xt = (signed char*)d_ws;
    signed char* wt = (signed char*)((char*)d_ws + WT_OFF);
    int*         bq = (int*)((char*)d_ws + BQ_OFF);

    hipLaunchKernelGGL(transform_x, dim3(N_IMG*PH), dim3(256), 0, stream, xq, xt);
    hipLaunchKernelGGL(quant_w, dim3(COUT), dim3(256), 0, stream,
                       weight, scale_x, bias, wt, bq, out + OUT_ELEMS);
    hipLaunchKernelGGL(conv_mfma, dim3(M_TOT/128, COUT/128), dim3(256), 0, stream,
                       xt, wt, bq, out);
}

// Round 17
// 72.767 us; speedup vs baseline: 1.5155x; 1.0050x over previous
//
#include <hip/hip_runtime.h>
#include <hip/hip_bf16.h>

typedef int   i32x4 __attribute__((ext_vector_type(4)));
typedef int   int4v __attribute__((ext_vector_type(4)));

#define N_IMG 64
#define CIN   256
#define COUT  256
#define HH    28
#define WW    28
#define PH    30
#define PW    30
#define M_TOT (N_IMG*HH*WW)          // 50176
#define OUT_ELEMS (N_IMG*COUT*HH*WW) // 12845056

// workspace layout (bytes) — all int8
#define XT_BYTES   ((size_t)N_IMG*PH*PW*CIN)       // 14745600
#define WT_OFF     (XT_BYTES)
#define WT_BYTES   ((size_t)9*COUT*CIN)            // 589824
#define BQ_OFF     (WT_OFF + WT_BYTES)             // 15335424

#define GLD16(g, l) __builtin_amdgcn_global_load_lds( \
    (const __attribute__((address_space(1))) void*)(g), \
    (__attribute__((address_space(3))) void*)(l), 16, 0, 0)

// ---------------------------------------------------------------------------
// Kernel 1 (merged prep): blocks 0..1919 = x transform; 1920..2175 = w quant.
//  Transform: x int32 NCHW -> padded int8 NHWC [N][30][30][256], value x-127,
//  PAD = -127 (conv_i8 + 127*sum(w) == true zero-padded conv). Vectorized:
//  int4 global loads (28-int rows are 16B-aligned), uchar4 packed stores.
//  Quant: per-co symmetric int8 weight quant; bq folds bias + 127*sum(w_q).
__global__ __launch_bounds__(256) void prep(const int* __restrict__ xq,
                                            const float* __restrict__ weight,
                                            const float* __restrict__ scale_x,
                                            const float* __restrict__ bias,
                                            signed char* __restrict__ xt,
                                            signed char* __restrict__ wt,
                                            int* __restrict__ bq,
                                            float* __restrict__ out_tail) {
    __shared__ int xs[CIN*28];               // transform: [ci][w] stride 28
    const int b = blockIdx.x;
    const int t = threadIdx.x;

    if (b < N_IMG*PH) {                      // ---- transform part
        const int n = b / PH, py = b % PH;
        signed char* dst = xt + ((size_t)(n*PH + py))*PW*CIN;
        if (py == 0 || py == PH-1) {
            int* d4 = (int*)dst;
            for (int i = t; i < PW*CIN/4; i += 256) d4[i] = 0x81818181; // -127
            return;
        }
        const int h = py - 1;
        const int* src = xq + (size_t)n*CIN*HH*WW + h*WW;
        for (int i = t; i < CIN*7; i += 256) {           // int4 loads
            const int ci = i / 7, q = i % 7;
            const int4v v = *(const int4v*)(src + ci*HH*WW + q*4);
            *(int4v*)&xs[ci*28 + q*4] = v;
        }
        __syncthreads();
        for (int i = t; i < PW*CIN/4; i += 256) {        // uchar4 stores
            const int px = i >> 6, ci0 = (i & 63) << 2;
            unsigned int o;
            if (px == 0 || px == PW-1) o = 0x81818181u;
            else {
                const int w = px - 1;
                const unsigned int b0 = (unsigned char)(xs[(ci0    )*28 + w] - 127);
                const unsigned int b1 = (unsigned char)(xs[(ci0 + 1)*28 + w] - 127);
                const unsigned int b2 = (unsigned char)(xs[(ci0 + 2)*28 + w] - 127);
                const unsigned int b3 = (unsigned char)(xs[(ci0 + 3)*28 + w] - 127);
                o = b0 | (b1 << 8) | (b2 << 16) | (b3 << 24);
            }
            ((unsigned int*)dst)[i] = o;
        }
        return;
    }

    // ---- quant part (co = b - 1920)
    float* red  = (float*)xs;                // reuse LDS
    int*   sred = (int*)xs + 256;
    const int co = b - N_IMG*PH;
    const float* wrow = weight + (size_t)co*CIN*9;
    float wv[9];
    float mx = 0.f;
    for (int it = 0; it < 9; ++it) {
        float v = wrow[it*256 + t];
        wv[it] = v;
        mx = fmaxf(mx, fabsf(v));
    }
    red[t] = mx;
    __syncthreads();
    for (int s = 128; s > 0; s >>= 1) {
        if (t < s) red[t] = fmaxf(red[t], red[t+s]);
        __syncthreads();
    }
    const float scale = fmaxf(red[0], 1e-8f) / 127.f;
    int isum = 0;
    for (int it = 0; it < 9; ++it) {
        const int i = it*256 + t;            // index over [ci][r][s]
        const int ci = i / 9, rs = i % 9;
        float q = rintf(wv[it] / scale);     // rintf = round-half-even = jnp.round
        q = fminf(fmaxf(q, -128.f), 127.f);
        const int qi = (int)q;
        isum += qi;
        wt[(size_t)rs*COUT*CIN + co*CIN + ci] = (signed char)qi;
    }
    sred[t] = isum;
    __syncthreads();
    for (int s = 128; s > 0; s >>= 1) {
        if (t < s) sred[t] += sred[t+s];
        __syncthreads();
    }
    if (t == 0) {
        const float so = scale * scale_x[0];
        out_tail[co] = so;
        bq[co] = (int)rintf(bias[co] / so) + 127 * sred[0];
    }
}

// ---------------------------------------------------------------------------
// Kernel 2: implicit-GEMM conv — IDENTICAL to round-16 winner.
// int8 MFMA, coalesced 128B staging runs, pre-swizzled global source ->
// linear LDS dest -> XOR-swizzled ds_read (rule #21), 2 blocks/CU.
// BM=128 x BN=128 x BK=128, 256 thr / 4 waves (2co x 2m), per-wave 64x64
// acc[4][4], 32 MFMA + 16 ds_read_b128 per tile, 18 K-tiles, LDS 64KB.
// Schedule = R6/R9 2-phase.  Bijective XCD swizzle (392 = 8x49).
__global__ __launch_bounds__(256, 2) void conv_mfma(const signed char* __restrict__ xt,
                                                    const signed char* __restrict__ wt,
                                                    const int* __restrict__ bq,
                                                    float* __restrict__ out) {
    __shared__ signed char Ash[2*16384];  // [buf][row128][128B] XOR-swizzled
    __shared__ signed char Bsh[2*16384];
    const int d = threadIdx.x;
    const int w4 = d >> 6;                   // wave id 0..3
    const int lane = d & 63, lr = lane & 15, kg = lane >> 4;
    const int wm = w4 >> 1, wn = w4 & 1;     // wave grid: 2 (co) x 2 (m)
    const int bx = blockIdx.x;               // 0..391
    const int mb = (bx & 7)*49 + (bx >> 3);  // bijective XCD swizzle (392=8*49)
    const int m0 = mb << 7;
    const int co0 = blockIdx.y << 7;

    // coalesced + pre-swizzled staging: 8 lanes/row x 16B = 128B run.
    const int srow = d >> 3;                 // 0..31
    const int skc  = (d & 7) ^ (srow & 7);
    const signed char* aS = wt + (size_t)(co0 + srow)*CIN + (skc << 4); // +j*32*CIN
    const signed char* bS[4];
#pragma unroll
    for (int j = 0; j < 4; ++j) {
        const int m = m0 + srow + j*32;
        const int n = m / 784, hw = m % 784, h = hw / 28, wq = hw % 28;
        bS[j] = xt + ((size_t)((n*PH + h)*PW + wq))*CIN + (skc << 4);
    }
    const int w4off = w4 << 10;              // wave-uniform LDS base (bytes)

    i32x4 acc[4][4] = {};

    // frag read byte bases (XOR-swizzled); ks=1 flips bit 6
    const int a0 = (wm*64 + lr)*128 + ((kg ^ (lr & 7)) << 4);
    const int b0 = (wn*64 + lr)*128 + ((kg ^ (lr & 7)) << 4);

#define STAGE(T_, P_) do { \
    const int tap_ = (T_) >> 1, c_ = (T_) & 1; \
    const int r3_ = (tap_*171) >> 9; \
    const int ao_ = tap_*(COUT*CIN) + (c_ << 7); \
    const int bo_ = ((r3_*PW + (tap_ - r3_*3)) << 8) + (c_ << 7); \
    GLD16(aS + ao_,         Ash + (P_)*16384 +         w4off); \
    GLD16(aS + ao_ +  8192, Ash + (P_)*16384 +  4096 + w4off); \
    GLD16(aS + ao_ + 16384, Ash + (P_)*16384 +  8192 + w4off); \
    GLD16(aS + ao_ + 24576, Ash + (P_)*16384 + 12288 + w4off); \
    GLD16(bS[0] + bo_,      Bsh + (P_)*16384 +         w4off); \
    GLD16(bS[1] + bo_,      Bsh + (P_)*16384 +  4096 + w4off); \
    GLD16(bS[2] + bo_,      Bsh + (P_)*16384 +  8192 + w4off); \
    GLD16(bS[3] + bo_,      Bsh + (P_)*16384 + 12288 + w4off); \
} while (0)

#define COMPUTE(P_) do { \
    const signed char* A_ = Ash + (P_)*16384; \
    const signed char* B_ = Bsh + (P_)*16384; \
    _Pragma("unroll") \
    for (int ks = 0; ks < 2; ++ks) { \
        const int ar = a0 ^ (ks << 6); \
        const int br = b0 ^ (ks << 6); \
        i32x4 af[4], bf[4]; \
        _Pragma("unroll") \
        for (int mr = 0; mr < 4; ++mr) \
            af[mr] = *(const i32x4*)&A_[ar + mr*2048]; \
        _Pragma("unroll") \
        for (int nr = 0; nr < 4; ++nr) \
            bf[nr] = *(const i32x4*)&B_[br + nr*2048]; \
        _Pragma("unroll") \
        for (int mr = 0; mr < 4; ++mr) \
            _Pragma("unroll") \
            for (int nr = 0; nr < 4; ++nr) \
                acc[mr][nr] = __builtin_amdgcn_mfma_i32_16x16x64_i8( \
                    af[mr], bf[nr], acc[mr][nr], 0, 0, 0); \
    } \
} while (0)

#define SYNCPT() do { \
    asm volatile("s_waitcnt vmcnt(0) lgkmcnt(0)" ::: "memory"); \
    __builtin_amdgcn_s_barrier(); \
    __builtin_amdgcn_sched_barrier(0); \
} while (0)

    STAGE(0, 0);
#pragma unroll 1
    for (int tt = 0; tt < 18; tt += 2) {
        SYNCPT();                       // tile tt landed
        STAGE(tt + 1, 1);               // prefetch next into spare buffer
        COMPUTE(0);                     // tile tt
        SYNCPT();                       // tile tt+1 landed
        if (tt < 16) STAGE(tt + 2, 0);
        COMPUTE(1);                     // tile tt+1
    }

    // epilogue: D row = co (kg*4+rg), col = m (lr); 64B coalesced runs
#pragma unroll
    for (int nr = 0; nr < 4; ++nr) {
        const int mm = m0 + wn*64 + nr*16 + lr;
        const int nn = mm / 784, hw2 = mm % 784;
        float* orow = out + (size_t)nn*COUT*784 + hw2;
#pragma unroll
        for (int mr = 0; mr < 4; ++mr) {
            const int co = co0 + wm*64 + mr*16 + kg*4;
#pragma unroll
            for (int rg = 0; rg < 4; ++rg)
                orow[(size_t)(co + rg)*784] = (float)(acc[mr][nr][rg] + bq[co + rg]);
        }
    }
#undef STAGE
#undef COMPUTE
#undef SYNCPT
}

// ---------------------------------------------------------------------------
extern "C" void kernel_launch(void* const* d_in, const int* in_sizes, int n_in,
                              void* d_out, int out_size, void* d_ws, size_t ws_size,
                              hipStream_t stream) {
    const int*   xq      = (const int*)d_in[0];
    const float* scale_x = (const float*)d_in[1];
    const float* weight  = (const float*)d_in[2];
    const float* bias    = (const float*)d_in[3];
    float* out = (float*)d_out;

    signed char* xt = (signed char*)d_ws;
    signed char* wt = (signed char*)((char*)d_ws + WT_OFF);
    int*         bq = (int*)((char*)d_ws + BQ_OFF);

    hipLaunchKernelGGL(prep, dim3(N_IMG*PH + COUT), dim3(256), 0, stream,
                       xq, weight, scale_x, bias, xt, wt, bq, out + OUT_ELEMS);
    hipLaunchKernelGGL(conv_mfma, dim3(M_TOT/128, COUT/128), dim3(256), 0, stream,
                       xt, wt, bq, out);
}

// Round 18
// 67.053 us; speedup vs baseline: 1.6447x; 1.0852x over previous
//
#include <hip/hip_runtime.h>
#include <hip/hip_bf16.h>

typedef int   i32x4 __attribute__((ext_vector_type(4)));
typedef int   int4v __attribute__((ext_vector_type(4)));

#define N_IMG 64
#define CIN   256
#define COUT  256
#define HH    28
#define WW    28
#define PH    30
#define PW    30
#define M_TOT (N_IMG*HH*WW)          // 50176
#define OUT_ELEMS (N_IMG*COUT*HH*WW) // 12845056

// workspace layout (bytes) — all int8
#define XT_BYTES   ((size_t)N_IMG*PH*PW*CIN)       // 14745600
#define WT_OFF     (XT_BYTES)
#define WT_BYTES   ((size_t)9*COUT*CIN)            // 589824
#define BQ_OFF     (WT_OFF + WT_BYTES)             // 15335424

#define GLD16(g, l) __builtin_amdgcn_global_load_lds( \
    (const __attribute__((address_space(1))) void*)(g), \
    (__attribute__((address_space(3))) void*)(l), 16, 0, 0)

// ---------------------------------------------------------------------------
// Kernel 1 (merged prep): blocks 0..1919 = x transform; 1920..2175 = w quant.
//  Transform: x int32 NCHW -> padded int8 NHWC [N][30][30][256], value x-127,
//  PAD = -127 (conv_i8 + 127*sum(w) == true zero-padded conv).
//  LDS tile padded to stride 29: pack-phase scalar reads step 116 ints ->
//  8 banks (8-way) instead of stride-28's 2 banks (32-way, R17's hidden cost).
//  Quant: per-co symmetric int8 weight quant; bq folds bias + 127*sum(w_q).
__global__ __launch_bounds__(256) void prep(const int* __restrict__ xq,
                                            const float* __restrict__ weight,
                                            const float* __restrict__ scale_x,
                                            const float* __restrict__ bias,
                                            signed char* __restrict__ xt,
                                            signed char* __restrict__ wt,
                                            int* __restrict__ bq,
                                            float* __restrict__ out_tail) {
    __shared__ int xs[CIN*29 + 4];           // [ci][w] stride 29 (+pad slack)
    const int b = blockIdx.x;
    const int t = threadIdx.x;

    if (b < N_IMG*PH) {                      // ---- transform part
        const int n = b / PH, py = b % PH;
        signed char* dst = xt + ((size_t)(n*PH + py))*PW*CIN;
        if (py == 0 || py == PH-1) {
            int* d4 = (int*)dst;
            for (int i = t; i < PW*CIN/4; i += 256) d4[i] = 0x81818181; // -127
            return;
        }
        const int h = py - 1;
        const int* src = xq + (size_t)n*CIN*HH*WW + h*WW;
        for (int i = t; i < CIN*7; i += 256) {           // int4 loads
            const int ci = i / 7, q = i % 7;
            const int4v v = *(const int4v*)(src + ci*HH*WW + q*4);
            *(int4v*)&xs[ci*29 + q*4] = v;               // b128 LDS writes, ~2-way max
        }
        __syncthreads();
        for (int i = t; i < PW*CIN/4; i += 256) {        // uchar4 stores
            const int px = i >> 6, ci0 = (i & 63) << 2;
            unsigned int o;
            if (px == 0 || px == PW-1) o = 0x81818181u;
            else {
                const int w = px - 1;
                const unsigned int b0 = (unsigned char)(xs[(ci0    )*29 + w] - 127);
                const unsigned int b1 = (unsigned char)(xs[(ci0 + 1)*29 + w] - 127);
                const unsigned int b2 = (unsigned char)(xs[(ci0 + 2)*29 + w] - 127);
                const unsigned int b3 = (unsigned char)(xs[(ci0 + 3)*29 + w] - 127);
                o = b0 | (b1 << 8) | (b2 << 16) | (b3 << 24);
            }
            ((unsigned int*)dst)[i] = o;
        }
        return;
    }

    // ---- quant part (co = b - 1920)
    float* red  = (float*)xs;                // reuse LDS
    int*   sred = (int*)xs + 256;
    const int co = b - N_IMG*PH;
    const float* wrow = weight + (size_t)co*CIN*9;
    float wv[9];
    float mx = 0.f;
    for (int it = 0; it < 9; ++it) {
        float v = wrow[it*256 + t];
        wv[it] = v;
        mx = fmaxf(mx, fabsf(v));
    }
    red[t] = mx;
    __syncthreads();
    for (int s = 128; s > 0; s >>= 1) {
        if (t < s) red[t] = fmaxf(red[t], red[t+s]);
        __syncthreads();
    }
    const float scale = fmaxf(red[0], 1e-8f) / 127.f;
    int isum = 0;
    for (int it = 0; it < 9; ++it) {
        const int i = it*256 + t;            // index over [ci][r][s]
        const int ci = i / 9, rs = i % 9;
        float q = rintf(wv[it] / scale);     // rintf = round-half-even = jnp.round
        q = fminf(fmaxf(q, -128.f), 127.f);
        const int qi = (int)q;
        isum += qi;
        wt[(size_t)rs*COUT*CIN + co*CIN + ci] = (signed char)qi;
    }
    sred[t] = isum;
    __syncthreads();
    for (int s = 128; s > 0; s >>= 1) {
        if (t < s) sred[t] += sred[t+s];
        __syncthreads();
    }
    if (t == 0) {
        const float so = scale * scale_x[0];
        out_tail[co] = so;
        bq[co] = (int)rintf(bias[co] / so) + 127 * sred[0];
    }
}

// ---------------------------------------------------------------------------
// Kernel 2: implicit-GEMM conv — IDENTICAL to round-16/17 winner.
// int8 MFMA, coalesced 128B staging runs, pre-swizzled global source ->
// linear LDS dest -> XOR-swizzled ds_read (rule #21), 2 blocks/CU.
// BM=128 x BN=128 x BK=128, 256 thr / 4 waves (2co x 2m), per-wave 64x64
// acc[4][4], 32 MFMA + 16 ds_read_b128 per tile, 18 K-tiles, LDS 64KB.
// Schedule = R6/R9 2-phase.  Bijective XCD swizzle (392 = 8x49).
__global__ __launch_bounds__(256, 2) void conv_mfma(const signed char* __restrict__ xt,
                                                    const signed char* __restrict__ wt,
                                                    const int* __restrict__ bq,
                                                    float* __restrict__ out) {
    __shared__ signed char Ash[2*16384];  // [buf][row128][128B] XOR-swizzled
    __shared__ signed char Bsh[2*16384];
    const int d = threadIdx.x;
    const int w4 = d >> 6;                   // wave id 0..3
    const int lane = d & 63, lr = lane & 15, kg = lane >> 4;
    const int wm = w4 >> 1, wn = w4 & 1;     // wave grid: 2 (co) x 2 (m)
    const int bx = blockIdx.x;               // 0..391
    const int mb = (bx & 7)*49 + (bx >> 3);  // bijective XCD swizzle (392=8*49)
    const int m0 = mb << 7;
    const int co0 = blockIdx.y << 7;

    // coalesced + pre-swizzled staging: 8 lanes/row x 16B = 128B run.
    const int srow = d >> 3;                 // 0..31
    const int skc  = (d & 7) ^ (srow & 7);
    const signed char* aS = wt + (size_t)(co0 + srow)*CIN + (skc << 4); // +j*32*CIN
    const signed char* bS[4];
#pragma unroll
    for (int j = 0; j < 4; ++j) {
        const int m = m0 + srow + j*32;
        const int n = m / 784, hw = m % 784, h = hw / 28, wq = hw % 28;
        bS[j] = xt + ((size_t)((n*PH + h)*PW + wq))*CIN + (skc << 4);
    }
    const int w4off = w4 << 10;              // wave-uniform LDS base (bytes)

    i32x4 acc[4][4] = {};

    // frag read byte bases (XOR-swizzled); ks=1 flips bit 6
    const int a0 = (wm*64 + lr)*128 + ((kg ^ (lr & 7)) << 4);
    const int b0 = (wn*64 + lr)*128 + ((kg ^ (lr & 7)) << 4);

#define STAGE(T_, P_) do { \
    const int tap_ = (T_) >> 1, c_ = (T_) & 1; \
    const int r3_ = (tap_*171) >> 9; \
    const int ao_ = tap_*(COUT*CIN) + (c_ << 7); \
    const int bo_ = ((r3_*PW + (tap_ - r3_*3)) << 8) + (c_ << 7); \
    GLD16(aS + ao_,         Ash + (P_)*16384 +         w4off); \
    GLD16(aS + ao_ +  8192, Ash + (P_)*16384 +  4096 + w4off); \
    GLD16(aS + ao_ + 16384, Ash + (P_)*16384 +  8192 + w4off); \
    GLD16(aS + ao_ + 24576, Ash + (P_)*16384 + 12288 + w4off); \
    GLD16(bS[0] + bo_,      Bsh + (P_)*16384 +         w4off); \
    GLD16(bS[1] + bo_,      Bsh + (P_)*16384 +  4096 + w4off); \
    GLD16(bS[2] + bo_,      Bsh + (P_)*16384 +  8192 + w4off); \
    GLD16(bS[3] + bo_,      Bsh + (P_)*16384 + 12288 + w4off); \
} while (0)

#define COMPUTE(P_) do { \
    const signed char* A_ = Ash + (P_)*16384; \
    const signed char* B_ = Bsh + (P_)*16384; \
    _Pragma("unroll") \
    for (int ks = 0; ks < 2; ++ks) { \
        const int ar = a0 ^ (ks << 6); \
        const int br = b0 ^ (ks << 6); \
        i32x4 af[4], bf[4]; \
        _Pragma("unroll") \
        for (int mr = 0; mr < 4; ++mr) \
            af[mr] = *(const i32x4*)&A_[ar + mr*2048]; \
        _Pragma("unroll") \
        for (int nr = 0; nr < 4; ++nr) \
            bf[nr] = *(const i32x4*)&B_[br + nr*2048]; \
        _Pragma("unroll") \
        for (int mr = 0; mr < 4; ++mr) \
            _Pragma("unroll") \
            for (int nr = 0; nr < 4; ++nr) \
                acc[mr][nr] = __builtin_amdgcn_mfma_i32_16x16x64_i8( \
                    af[mr], bf[nr], acc[mr][nr], 0, 0, 0); \
    } \
} while (0)

#define SYNCPT() do { \
    asm volatile("s_waitcnt vmcnt(0) lgkmcnt(0)" ::: "memory"); \
    __builtin_amdgcn_s_barrier(); \
    __builtin_amdgcn_sched_barrier(0); \
} while (0)

    STAGE(0, 0);
#pragma unroll 1
    for (int tt = 0; tt < 18; tt += 2) {
        SYNCPT();                       // tile tt landed
        STAGE(tt + 1, 1);               // prefetch next into spare buffer
        COMPUTE(0);                     // tile tt
        SYNCPT();                       // tile tt+1 landed
        if (tt < 16) STAGE(tt + 2, 0);
        COMPUTE(1);                     // tile tt+1
    }

    // epilogue: D row = co (kg*4+rg), col = m (lr); 64B coalesced runs
#pragma unroll
    for (int nr = 0; nr < 4; ++nr) {
        const int mm = m0 + wn*64 + nr*16 + lr;
        const int nn = mm / 784, hw2 = mm % 784;
        float* orow = out + (size_t)nn*COUT*784 + hw2;
#pragma unroll
        for (int mr = 0; mr < 4; ++mr) {
            const int co = co0 + wm*64 + mr*16 + kg*4;
#pragma unroll
            for (int rg = 0; rg < 4; ++rg)
                orow[(size_t)(co + rg)*784] = (float)(acc[mr][nr][rg] + bq[co + rg]);
        }
    }
#undef STAGE
#undef COMPUTE
#undef SYNCPT
}

// ---------------------------------------------------------------------------
extern "C" void kernel_launch(void* const* d_in, const int* in_sizes, int n_in,
                              void* d_out, int out_size, void* d_ws, size_t ws_size,
                              hipStream_t stream) {
    const int*   xq      = (const int*)d_in[0];
    const float* scale_x = (const float*)d_in[1];
    const float* weight  = (const float*)d_in[2];
    const float* bias    = (const float*)d_in[3];
    float* out = (float*)d_out;

    signed char* xt = (signed char*)d_ws;
    signed char* wt = (signed char*)((char*)d_ws + WT_OFF);
    int*         bq = (int*)((char*)d_ws + BQ_OFF);

    hipLaunchKernelGGL(prep, dim3(N_IMG*PH + COUT), dim3(256), 0, stream,
                       xq, weight, scale_x, bias, xt, wt, bq, out + OUT_ELEMS);
    hipLaunchKernelGGL(conv_mfma, dim3(M_TOT/128, COUT/128), dim3(256), 0, stream,
                       xt, wt, bq, out);
}

// Round 20
// 66.669 us; speedup vs baseline: 1.6541x; 1.0058x over previous
//
#include <hip/hip_runtime.h>
#include <hip/hip_bf16.h>

typedef int   i32x4 __attribute__((ext_vector_type(4)));
typedef int   int4v __attribute__((ext_vector_type(4)));

#define N_IMG 64
#define CIN   256
#define COUT  256
#define HH    28
#define WW    28
#define PH    30
#define PW    30
#define M_TOT (N_IMG*HH*WW)          // 50176
#define OUT_ELEMS (N_IMG*COUT*HH*WW) // 12845056

// workspace layout (bytes) — all int8
#define XT_BYTES   ((size_t)N_IMG*PH*PW*CIN)       // 14745600
#define WT_OFF     (XT_BYTES)
#define WT_BYTES   ((size_t)9*COUT*CIN)            // 589824
#define BQ_OFF     (WT_OFF + WT_BYTES)             // 15335424

#define GLD16(g, l) __builtin_amdgcn_global_load_lds( \
    (const __attribute__((address_space(1))) void*)(g), \
    (__attribute__((address_space(3))) void*)(l), 16, 0, 0)

// ---------------------------------------------------------------------------
// Kernel 1 (merged prep): blocks 0..1919 = x transform; 1920..2175 = w quant.
//  Transform: x int32 NCHW -> padded int8 NHWC [N][30][30][256], value x-127,
//  PAD = -127 (conv_i8 + 127*sum(w) == true zero-padded conv).
//  LDS layout TRANSPOSED [w][ci], stride 260 ints (1040B = 65*16 -> every row
//  16B-aligned): pack phase reads 4 consecutive ci as ONE aligned
//  ds_read_b128, quad index == lane%8 -> conflict-free floor (R18's layout
//  cost 4 scalar reads x 8-way).  Load phase: coalesced int4 global reads,
//  4 scalar LDS writes at bank (4w+ci)%32 ~ 4-way.
//  Quant: per-co symmetric int8 weight quant; bq folds bias + 127*sum(w_q).
__global__ __launch_bounds__(256) void prep(const int* __restrict__ xq,
                                            const float* __restrict__ weight,
                                            const float* __restrict__ scale_x,
                                            const float* __restrict__ bias,
                                            signed char* __restrict__ xt,
                                            signed char* __restrict__ wt,
                                            int* __restrict__ bq,
                                            float* __restrict__ out_tail) {
    __shared__ int xs[28*260];               // [w][ci] stride 260
    const int b = blockIdx.x;
    const int t = threadIdx.x;

    if (b < N_IMG*PH) {                      // ---- transform part
        const int n = b / PH, py = b % PH;
        signed char* dst = xt + ((size_t)(n*PH + py))*PW*CIN;
        if (py == 0 || py == PH-1) {
            int* d4 = (int*)dst;
            for (int i = t; i < PW*CIN/4; i += 256) d4[i] = 0x81818181; // -127
            return;
        }
        const int h = py - 1;
        const int* src = xq + (size_t)n*CIN*HH*WW + h*WW;
        for (int i = t; i < CIN*7; i += 256) {           // coalesced int4 loads
            const int ci = i / 7, q = i % 7;
            const int4v v = *(const int4v*)(src + ci*HH*WW + q*4);
            xs[(4*q    )*260 + ci] = v.x;                // transposed scatter,
            xs[(4*q + 1)*260 + ci] = v.y;                // ~4-way banks
            xs[(4*q + 2)*260 + ci] = v.z;
            xs[(4*q + 3)*260 + ci] = v.w;
        }
        __syncthreads();
        for (int i = t; i < PW*CIN/4; i += 256) {        // pack + uchar4 store
            const int px = i >> 6, ci0 = (i & 63) << 2;
            unsigned int o;
            if (px == 0 || px == PW-1) o = 0x81818181u;
            else {
                const int4v v = *(const int4v*)&xs[(px - 1)*260 + ci0]; // b128, CF
                const unsigned int b0 = (unsigned char)(v.x - 127);
                const unsigned int b1 = (unsigned char)(v.y - 127);
                const unsigned int b2 = (unsigned char)(v.z - 127);
                const unsigned int b3 = (unsigned char)(v.w - 127);
                o = b0 | (b1 << 8) | (b2 << 16) | (b3 << 24);
            }
            ((unsigned int*)dst)[i] = o;
        }
        return;
    }

    // ---- quant part (co = b - 1920)
    float* red  = (float*)xs;                // reuse LDS
    int*   sred = (int*)xs + 256;
    const int co = b - N_IMG*PH;
    const float* wrow = weight + (size_t)co*CIN*9;
    float wv[9];
    float mx = 0.f;
    for (int it = 0; it < 9; ++it) {
        float v = wrow[it*256 + t];
        wv[it] = v;
        mx = fmaxf(mx, fabsf(v));
    }
    red[t] = mx;
    __syncthreads();
    for (int s = 128; s > 0; s >>= 1) {
        if (t < s) red[t] = fmaxf(red[t], red[t+s]);
        __syncthreads();
    }
    const float scale = fmaxf(red[0], 1e-8f) / 127.f;
    int isum = 0;
    for (int it = 0; it < 9; ++it) {
        const int i = it*256 + t;            // index over [ci][r][s]
        const int ci = i / 9, rs = i % 9;
        float q = rintf(wv[it] / scale);     // rintf = round-half-even = jnp.round
        q = fminf(fmaxf(q, -128.f), 127.f);
        const int qi = (int)q;
        isum += qi;
        wt[(size_t)rs*COUT*CIN + co*CIN + ci] = (signed char)qi;
    }
    sred[t] = isum;
    __syncthreads();
    for (int s = 128; s > 0; s >>= 1) {
        if (t < s) sred[t] += sred[t+s];
        __syncthreads();
    }
    if (t == 0) {
        const float so = scale * scale_x[0];
        out_tail[co] = so;
        bq[co] = (int)rintf(bias[co] / so) + 127 * sred[0];
    }
}

// ---------------------------------------------------------------------------
// Kernel 2: implicit-GEMM conv — IDENTICAL to round-16/17/18 winner.
// int8 MFMA, coalesced 128B staging runs, pre-swizzled global source ->
// linear LDS dest -> XOR-swizzled ds_read (rule #21), 2 blocks/CU.
// BM=128 x BN=128 x BK=128, 256 thr / 4 waves (2co x 2m), per-wave 64x64
// acc[4][4], 32 MFMA + 16 ds_read_b128 per tile, 18 K-tiles, LDS 64KB.
// Schedule = R6/R9 2-phase.  Bijective XCD swizzle (392 = 8x49).
__global__ __launch_bounds__(256, 2) void conv_mfma(const signed char* __restrict__ xt,
                                                    const signed char* __restrict__ wt,
                                                    const int* __restrict__ bq,
                                                    float* __restrict__ out) {
    __shared__ signed char Ash[2*16384];  // [buf][row128][128B] XOR-swizzled
    __shared__ signed char Bsh[2*16384];
    const int d = threadIdx.x;
    const int w4 = d >> 6;                   // wave id 0..3
    const int lane = d & 63, lr = lane & 15, kg = lane >> 4;
    const int wm = w4 >> 1, wn = w4 & 1;     // wave grid: 2 (co) x 2 (m)
    const int bx = blockIdx.x;               // 0..391
    const int mb = (bx & 7)*49 + (bx >> 3);  // bijective XCD swizzle (392=8*49)
    const int m0 = mb << 7;
    const int co0 = blockIdx.y << 7;

    // coalesced + pre-swizzled staging: 8 lanes/row x 16B = 128B run.
    const int srow = d >> 3;                 // 0..31
    const int skc  = (d & 7) ^ (srow & 7);
    const signed char* aS = wt + (size_t)(co0 + srow)*CIN + (skc << 4); // +j*32*CIN
    const signed char* bS[4];
#pragma unroll
    for (int j = 0; j < 4; ++j) {
        const int m = m0 + srow + j*32;
        const int n = m / 784, hw = m % 784, h = hw / 28, wq = hw % 28;
        bS[j] = xt + ((size_t)((n*PH + h)*PW + wq))*CIN + (skc << 4);
    }
    const int w4off = w4 << 10;              // wave-uniform LDS base (bytes)

    i32x4 acc[4][4] = {};

    // frag read byte bases (XOR-swizzled); ks=1 flips bit 6
    const int a0 = (wm*64 + lr)*128 + ((kg ^ (lr & 7)) << 4);
    const int b0 = (wn*64 + lr)*128 + ((kg ^ (lr & 7)) << 4);

#define STAGE(T_, P_) do { \
    const int tap_ = (T_) >> 1, c_ = (T_) & 1; \
    const int r3_ = (tap_*171) >> 9; \
    const int ao_ = tap_*(COUT*CIN) + (c_ << 7); \
    const int bo_ = ((r3_*PW + (tap_ - r3_*3)) << 8) + (c_ << 7); \
    GLD16(aS + ao_,         Ash + (P_)*16384 +         w4off); \
    GLD16(aS + ao_ +  8192, Ash + (P_)*16384 +  4096 + w4off); \
    GLD16(aS + ao_ + 16384, Ash + (P_)*16384 +  8192 + w4off); \
    GLD16(aS + ao_ + 24576, Ash + (P_)*16384 + 12288 + w4off); \
    GLD16(bS[0] + bo_,      Bsh + (P_)*16384 +         w4off); \
    GLD16(bS[1] + bo_,      Bsh + (P_)*16384 +  4096 + w4off); \
    GLD16(bS[2] + bo_,      Bsh + (P_)*16384 +  8192 + w4off); \
    GLD16(bS[3] + bo_,      Bsh + (P_)*16384 + 12288 + w4off); \
} while (0)

#define COMPUTE(P_) do { \
    const signed char* A_ = Ash + (P_)*16384; \
    const signed char* B_ = Bsh + (P_)*16384; \
    _Pragma("unroll") \
    for (int ks = 0; ks < 2; ++ks) { \
        const int ar = a0 ^ (ks << 6); \
        const int br = b0 ^ (ks << 6); \
        i32x4 af[4], bf[4]; \
        _Pragma("unroll") \
        for (int mr = 0; mr < 4; ++mr) \
            af[mr] = *(const i32x4*)&A_[ar + mr*2048]; \
        _Pragma("unroll") \
        for (int nr = 0; nr < 4; ++nr) \
            bf[nr] = *(const i32x4*)&B_[br + nr*2048]; \
        _Pragma("unroll") \
        for (int mr = 0; mr < 4; ++mr) \
            _Pragma("unroll") \
            for (int nr = 0; nr < 4; ++nr) \
                acc[mr][nr] = __builtin_amdgcn_mfma_i32_16x16x64_i8( \
                    af[mr], bf[nr], acc[mr][nr], 0, 0, 0); \
    } \
} while (0)

#define SYNCPT() do { \
    asm volatile("s_waitcnt vmcnt(0) lgkmcnt(0)" ::: "memory"); \
    __builtin_amdgcn_s_barrier(); \
    __builtin_amdgcn_sched_barrier(0); \
} while (0)

    STAGE(0, 0);
#pragma unroll 1
    for (int tt = 0; tt < 18; tt += 2) {
        SYNCPT();                       // tile tt landed
        STAGE(tt + 1, 1);               // prefetch next into spare buffer
        COMPUTE(0);                     // tile tt
        SYNCPT();                       // tile tt+1 landed
        if (tt < 16) STAGE(tt + 2, 0);
        COMPUTE(1);                     // tile tt+1
    }

    // epilogue: D row = co (kg*4+rg), col = m (lr); 64B coalesced runs
#pragma unroll
    for (int nr = 0; nr < 4; ++nr) {
        const int mm = m0 + wn*64 + nr*16 + lr;
        const int nn = mm / 784, hw2 = mm % 784;
        float* orow = out + (size_t)nn*COUT*784 + hw2;
#pragma unroll
        for (int mr = 0; mr < 4; ++mr) {
            const int co = co0 + wm*64 + mr*16 + kg*4;
#pragma unroll
            for (int rg = 0; rg < 4; ++rg)
                orow[(size_t)(co + rg)*784] = (float)(acc[mr][nr][rg] + bq[co + rg]);
        }
    }
#undef STAGE
#undef COMPUTE
#undef SYNCPT
}

// ---------------------------------------------------------------------------
extern "C" void kernel_launch(void* const* d_in, const int* in_sizes, int n_in,
                              void* d_out, int out_size, void* d_ws, size_t ws_size,
                              hipStream_t stream) {
    const int*   xq      = (const int*)d_in[0];
    const float* scale_x = (const float*)d_in[1];
    const float* weight  = (const float*)d_in[2];
    const float* bias    = (const float*)d_in[3];
    float* out = (float*)d_out;

    signed char* xt = (signed char*)d_ws;
    signed char* wt = (signed char*)((char*)d_ws + WT_OFF);
    int*         bq = (int*)((char*)d_ws + BQ_OFF);

    hipLaunchKernelGGL(prep, dim3(N_IMG*PH + COUT), dim3(256), 0, stream,
                       xq, weight, scale_x, bias, xt, wt, bq, out + OUT_ELEMS);
    hipLaunchKernelGGL(conv_mfma, dim3(M_TOT/128, COUT/128), dim3(256), 0, stream,
                       xt, wt, bq, out);
}